// Round 3
// baseline (360.776 us; speedup 1.0000x reference)
//
#include <hip/hip_runtime.h>

#define NBG   60
#define LMAX  30
#define MWC   59
#define CTR   29
#define NPAIR 20
#define PI_F  3.14159265358979323846f
#define PI_D  3.14159265358979323846

// ---------------------------------------------------------------------------
// f32 Wigner small-d column scale*d^l_{mp,mn}(beta), l=0..29, Jacobi
// recurrence (convention == expm(-(beta/2)(J+ - J-)), verified r1/r2).
// ---------------------------------------------------------------------------
__device__ void wigner_colf(float beta, int mp, int mn, float scale,
                            float* out, int stride) {
  int a = mp - mn; if (a < 0) a = -a;
  int b = mp + mn; if (b < 0) b = -b;
  int lmin = (a + b) >> 1;
  for (int l = 0; l < LMAX; ++l) out[l * stride] = 0.0f;
  float sh, ch; sincosf(0.5f * beta, &sh, &ch);
  float x = ch * ch - sh * sh;
  float base = scale;
  for (int q = 0; q < a; ++q) base *= sh;
  for (int q = 0; q < b; ++q) base *= ch;
  if (mp >= mn && ((mp - mn) & 1)) base = -base;
  float K2 = 1.f;
  for (int q = 1; q <= a; ++q) K2 *= (float)(b + q) / (float)q;
  float Pm2 = 0.f, Pm1 = 1.f;
  out[lmin * stride] = base * sqrtf(K2);
  for (int s = 1; lmin + s < LMAX; ++s) {
    float Ps;
    if (s == 1) {
      Ps = (a + 1) + (a + b + 2) * 0.5f * (x - 1.f);
    } else {
      float t0 = 2.f * s + a + b;
      float c1 = 2.f * s * (s + a + b) * (t0 - 2.f);
      float c2 = (t0 - 1.f) * (t0 * (t0 - 2.f) * x + (float)(a * a - b * b));
      float c3 = 2.f * (s + a - 1.f) * (s + b - 1.f) * t0;
      Ps = (c2 * Pm1 - c3 * Pm2) / c1;
    }
    K2 *= ((float)s * (s + a + b)) / (((float)s + a) * ((float)s + b));
    out[(lmin + s) * stride] = base * sqrtf(K2) * Ps;
    Pm2 = Pm1; Pm1 = Ps;
  }
}

// ---------------------------------------------------------------------------
// K_prep (62 blocks x 64):
//  block 0      : scwF1/scwF2[N][pair] = wqn[N] * (sum_p w[pair,p] e^{+i n a_p})
//  block 1      : dkn[l][N] = d^l_{N-29,0}(pi/160)
//  blocks 2..61 : D0w[j][l][M] = wq[j] * d^l_{M-29,0}(beta_j)
// Twiddles use exact integer-mod range reduction.
// ---------------------------------------------------------------------------
__global__ __launch_bounds__(64)
void k_prep(const float* __restrict__ wc, const float* __restrict__ wd,
            float2* __restrict__ scwF1, float2* __restrict__ scwF2,
            float* __restrict__ dkn, float* __restrict__ D0w) {
  int bi = blockIdx.x, t = threadIdx.x;
  if (bi == 0) {
    __shared__ float swq[NBG];
    __shared__ float2 swqn[MWC];
    if (t < NBG) {
      float s = 0.f;
      for (int k = 0; k < 30; ++k) {
        int r = ((2 * t + 1) * (2 * k + 1)) % 240;           // sin(pi*r/120)
        s += sinf(2.f * PI_F * r / 240.f) / (float)(2 * k + 1);
      }
      swq[t] = (2.f / 30.f) * sinf(PI_F * (2 * t + 1) / 120.f) * s;
    }
    __syncthreads();
    if (t < MWC) {
      int n = t - CTR;
      float re = 0.f, im = 0.f;
      for (int g = 0; g < NBG; ++g) {
        int k = ((n * g) % NBG + NBG) % NBG;
        float sn, cs; sincosf(2.f * PI_F * k / 60.f, &sn, &cs);
        re += swq[g] * cs; im += swq[g] * sn;
      }
      swqn[t] = make_float2(re, im);
    }
    __syncthreads();
    for (int idx = t; idx < MWC * NPAIR; idx += 64) {
      int N = idx / NPAIR, pair = idx - N * NPAIR, n = N - CTR;
      float re1 = 0, im1 = 0, re2 = 0, im2 = 0;
      for (int p = 0; p < 6; ++p) {
        int k = ((n * p) % 6 + 6) % 6;
        float sn, cs; sincosf(2.f * PI_F * k / 6.f, &sn, &cs);
        float a1 = wc[pair * 6 + p], a2 = wd[pair * 6 + p];
        re1 += a1 * cs; im1 += a1 * sn;
        re2 += a2 * cs; im2 += a2 * sn;
      }
      float2 w = swqn[N];
      scwF1[idx] = make_float2(w.x * re1 - w.y * im1, w.x * im1 + w.y * re1);
      scwF2[idx] = make_float2(w.x * re2 - w.y * im2, w.x * im2 + w.y * re2);
    }
  } else if (bi == 1) {
    if (t < MWC) wigner_colf(PI_F / 160.f, t - CTR, 0, 1.f, dkn + t, MWC);
  } else {
    int j = bi - 2;
    if (t < MWC) {
      float s = 0.f;
      for (int k = 0; k < 30; ++k) {
        int r = ((2 * j + 1) * (2 * k + 1)) % 240;
        s += sinf(2.f * PI_F * r / 240.f) / (float)(2 * k + 1);
      }
      float wqj = (2.f / 30.f) * sinf(PI_F * (2 * j + 1) / 120.f) * s;
      wigner_colf(PI_F * (2 * j + 1) / 120.f, t - CTR, 0, wqj,
                  D0w + (size_t)j * LMAX * MWC + t, MWC);
    }
  }
}

// ---------------------------------------------------------------------------
// K_fa1: fused alpha-DFT + S2 analysis, stage 1. Block per bi = b*2+i.
// X2[M][l][i][b] = sum_j D0w[j,l,M] * (2pi/60) * DFT_a(x[bi,j,:])[M]
// ---------------------------------------------------------------------------
__global__ __launch_bounds__(256)
void k_fa1(const float* __restrict__ xin, const float* __restrict__ D0w,
           float2* __restrict__ X2) {
  __shared__ float xr[NBG * NBG];
  __shared__ float2 xf[NBG][MWC];
  __shared__ float twc[NBG], tws[NBG];
  int bi = blockIdx.x, t = threadIdx.x;
  int b = bi >> 1, i = bi & 1;
  for (int q = t; q < NBG * NBG; q += 256) xr[q] = xin[(size_t)bi * NBG * NBG + q];
  if (t < NBG) {
    float s, c; sincosf(-2.f * PI_F * t / 60.f, &s, &c);
    twc[t] = c; tws[t] = s;
  }
  __syncthreads();
  for (int q = t; q < NBG * MWC; q += 256) {
    int j = q / MWC, M = q - j * MWC, mm = M - CTR;
    const float* xp = xr + j * NBG;
    float re = 0.f, im = 0.f; int k = 0;
    for (int a = 0; a < NBG; ++a) {
      re += xp[a] * twc[k]; im += xp[a] * tws[k];
      k += mm; if (k >= NBG) k -= NBG; if (k < 0) k += NBG;
    }
    const float sc = 2.f * PI_F / 60.f;
    xf[j][M] = make_float2(re * sc, im * sc);
  }
  __syncthreads();
  for (int q = t; q < LMAX * MWC; q += 256) {
    int l = q / MWC, M = q - l * MWC;
    float re = 0.f, im = 0.f;
    for (int j = 0; j < NBG; ++j) {
      float w = D0w[((size_t)j * LMAX + l) * MWC + M];
      float2 v = xf[j][M];
      re += w * v.x; im += w * v.y;
    }
    X2[((M * LMAX + l) * 2 + i) * 16 + b] = make_float2(re, im);
  }
}

// ---------------------------------------------------------------------------
// K_an2: stage-2 analysis directly from T1 via the synth/fft identity:
//   xfc2[m] = pi * (T1[m] + conj(T1[-m]))     (ifft_a then fft_a collapse)
// X2[M][l][i][b] = sum_j D0w[j,l,M] * xfc2[bi,j,M]
// ---------------------------------------------------------------------------
__global__ __launch_bounds__(256)
void k_an2(const float2* __restrict__ T1, const float* __restrict__ D0w,
           float2* __restrict__ X2) {
  __shared__ float2 tf[NBG][MWC];
  int bi = blockIdx.x, t = threadIdx.x;   // bi = b*10 + i
  int b = bi / 10, i = bi - 10 * b;
  for (int q = t; q < NBG * MWC; q += 256)
    ((float2*)tf)[q] = T1[(size_t)bi * NBG * MWC + q];
  __syncthreads();
  for (int q = t; q < LMAX * MWC; q += 256) {
    int l = q / MWC, M = q - l * MWC;
    float re = 0.f, im = 0.f;
    for (int j = 0; j < NBG; ++j) {
      float w = D0w[((size_t)j * LMAX + l) * MWC + M];
      float2 zM = tf[j][M], zN = tf[j][58 - M];
      re += w * (zM.x + zN.x);
      im += w * (zM.y - zN.y);
    }
    X2[((M * LMAX + l) * 10 + i) * 16 + b] = make_float2(PI_F * re, PI_F * im);
  }
}

// ---------------------------------------------------------------------------
// K_core<CI,CO>: one 64-thr block per (j,M).  LDS = 12 KB -> ~13 waves/CU.
//  phase1: lane N: f32 Wigner recurrence -> sgR[l][N] = d * dkn[l,N]  (real)
//  phase2: sC[l][pair] = (2l+1) * sum_N sgR[l][N] * scwF[N][pair]  (static 59)
//  phase3: T[u][j][M] = sum_{i,l} X2[M,l,i,b] * sC[l][i*CO+o]
// ---------------------------------------------------------------------------
template <int CI, int CO>
__global__ __launch_bounds__(64)
void k_core(const float2* __restrict__ X2, const float* __restrict__ dkn,
            const float2* __restrict__ scwF, float2* __restrict__ T) {
  constexpr int UU = 16 * CO;
  __shared__ float sgR[LMAX][NBG];     // [l][N], 7200 B (N padded to 60)
  __shared__ float2 sC[LMAX][NPAIR];   // 4800 B
  int jm = blockIdx.x, t = threadIdx.x;
  int j = jm / MWC, M = jm - j * MWC;
  int mp = M - CTR;
  int am = mp < 0 ? -mp : mp;

  if (t < MWC) {
    int N = t, mn = N - CTR;
    for (int l = 0; l < LMAX; ++l) sgR[l][N] = 0.f;
    int a = mp - mn; if (a < 0) a = -a;
    int bq = mp + mn; if (bq < 0) bq = -bq;
    int lmin = (a + bq) >> 1;
    float beta = (float)(PI_D * (2.0 * j + 1.0) / 120.0);
    float sh, ch; sincosf(0.5f * beta, &sh, &ch);
    float x = ch * ch - sh * sh;
    float base = 1.f;
    for (int q = 0; q < a; ++q) base *= sh;
    for (int q = 0; q < bq; ++q) base *= ch;
    if (mp >= mn && ((mp - mn) & 1)) base = -base;
    float K2 = 1.f;
    for (int q = 1; q <= a; ++q) K2 *= (float)(bq + q) / (float)q;
    float Pm2 = 0.f, Pm1 = 1.f;
    sgR[lmin][N] = base * sqrtf(K2) * dkn[lmin * MWC + N];
    for (int s = 1; lmin + s < LMAX; ++s) {
      float Ps;
      if (s == 1) {
        Ps = (a + 1) + (a + bq + 2) * 0.5f * (x - 1.f);
      } else {
        float t0 = 2.f * s + a + bq;
        float c1 = 2.f * s * (s + a + bq) * (t0 - 2.f);
        float c2 = (t0 - 1.f) * (t0 * (t0 - 2.f) * x + (float)(a * a - bq * bq));
        float c3 = 2.f * (s + a - 1.f) * (s + bq - 1.f) * t0;
        Ps = (c2 * Pm1 - c3 * Pm2) / c1;
      }
      K2 *= ((float)s * (s + a + bq)) / (((float)s + a) * ((float)s + bq));
      sgR[lmin + s][N] = base * sqrtf(K2) * Ps * dkn[(lmin + s) * MWC + N];
      Pm2 = Pm1; Pm1 = Ps;
    }
  }
  __syncthreads();

  int qbase = am * NPAIR;
  for (int q = t; q < qbase; q += 64) ((float2*)sC)[q] = make_float2(0.f, 0.f);
  for (int q = qbase + t; q < LMAX * NPAIR; q += 64) {
    int l = q / NPAIR, pair = q - l * NPAIR;
    float cre = 0.f, cim = 0.f;
#pragma unroll
    for (int N = 0; N < MWC; ++N) {
      float g = sgR[l][N];
      float2 c = scwF[N * NPAIR + pair];
      cre += g * c.x; cim += g * c.y;
    }
    float fac = (float)(2 * l + 1);
    ((float2*)sC)[q] = make_float2(fac * cre, fac * cim);
  }
  __syncthreads();

  if constexpr (CO == 10) {
    for (int u = t; u < UU; u += 64) {
      int bb = u / CO, o = u - CO * bb;
      float tre = 0.f, tim = 0.f;
      for (int i = 0; i < CI; ++i) {
        const float2* cp = &sC[0][i * CO + o];
#pragma unroll
        for (int l = 0; l < LMAX; ++l) {
          float2 xv = X2[((M * LMAX + l) * CI + i) * 16 + bb];
          float2 cv = cp[l * NPAIR];
          tre += xv.x * cv.x - xv.y * cv.y;
          tim += xv.x * cv.y + xv.y * cv.x;
        }
      }
      T[((size_t)u * NBG + j) * MWC + M] = make_float2(tre, tim);
    }
  } else {
    int u = t & 31, sub = t >> 5;
    int bb = u >> 1, o = u & 1;
    float tre = 0.f, tim = 0.f;
    for (int i = 0; i < CI; ++i) {
      const float2* cp = &sC[0][i * CO + o];
#pragma unroll
      for (int k = 0; k < 15; ++k) {
        int l = sub + 2 * k;
        float2 xv = X2[((M * LMAX + l) * CI + i) * 16 + bb];
        float2 cv = cp[l * NPAIR];
        tre += xv.x * cv.x - xv.y * cv.y;
        tim += xv.x * cv.y + xv.y * cv.x;
      }
    }
    tre += __shfl_xor(tre, 32);
    tim += __shfl_xor(tim, 32);
    if (sub == 0) T[((size_t)u * NBG + j) * MWC + M] = make_float2(tre, tim);
  }
}

// ---------------------------------------------------------------------------
// K_synth: final alpha-synthesis (real part). Block per row r=(u,j), u=b*2+o.
// ---------------------------------------------------------------------------
__global__ __launch_bounds__(64)
void k_synth(const float2* __restrict__ T2, float* __restrict__ out) {
  __shared__ float2 Tr[MWC];
  __shared__ float twc[NBG], tws[NBG];
  int r = blockIdx.x, t = threadIdx.x;
  if (t < MWC) Tr[t] = T2[(size_t)r * MWC + t];
  if (t < NBG) {
    float s, c; sincosf(2.f * PI_F * t / 60.f, &s, &c);
    twc[t] = c; tws[t] = s;
  }
  __syncthreads();
  if (t < NBG) {
    float acc = 0.f;
    int k = (NBG - (29 * t) % NBG) % NBG;   // (-29*t) mod 60
    for (int Mi = 0; Mi < MWC; ++Mi) {
      float2 v = Tr[Mi];
      acc += v.x * twc[k] - v.y * tws[k];
      k += t; if (k >= NBG) k -= NBG;
    }
    out[(size_t)r * NBG + t] = acc;
  }
}

// ---------------------------------------------------------------------------
extern "C" void kernel_launch(void* const* d_in, const int* in_sizes, int n_in,
                              void* d_out, int out_size, void* d_ws, size_t ws_size,
                              hipStream_t stream) {
  const float* x1       = (const float*)d_in[0];
  const float* w_conv   = (const float*)d_in[1];
  const float* w_deconv = (const float*)d_in[2];
  float* out = (float*)d_out;
  char* ws = (char*)d_ws;

  float2* scwF1 = (float2*)(ws + 0);        // 59*20 c64   = 9440
  float2* scwF2 = (float2*)(ws + 9728);     // 9440
  float*  dkn   = (float*) (ws + 19456);    // 30*59 f32   = 7080
  float*  D0w   = (float*) (ws + 26880);    // 60*30*59 f32 = 424800
  float2* X21   = (float2*)(ws + 452096);   // 59*30*2*16 c64 = 453120
  float2* X22   = (float2*)(ws + 905728);   // 59*30*10*16 c64 = 2265600
  float2* T1    = (float2*)(ws + 3171840);  // 160*60*59 c64 = 4531200
  float2* T2    = (float2*)(ws + 7703552);  // 32*60*59 c64 = 906240
  // total 8609792 B (< 9.1 MB proven available in r1/r2)

  k_prep<<<NBG + 2, 64, 0, stream>>>(w_conv, w_deconv, scwF1, scwF2, dkn, D0w);
  k_fa1<<<16 * 2, 256, 0, stream>>>(x1, D0w, X21);
  k_core<2, 10><<<NBG * MWC, 64, 0, stream>>>(X21, dkn, scwF1, T1);
  k_an2<<<16 * 10, 256, 0, stream>>>(T1, D0w, X22);
  k_core<10, 2><<<NBG * MWC, 64, 0, stream>>>(X22, dkn, scwF2, T2);
  k_synth<<<16 * 2 * NBG, 64, 0, stream>>>(T2, out);
}

// Round 4
// 194.046 us; speedup vs baseline: 1.8592x; 1.8592x over previous
//
#include <hip/hip_runtime.h>

#define NBG   60
#define LMAX  30
#define MWC   59
#define CTR   29
#define NPAIR 20
#define NT    17          // truncated n-window |n|<=8 (dk ~ (beta/2)^|n|, beta=pi/160)
#define NOFF  8
#define PI_F  3.14159265358979323846f
#define PI_D  3.14159265358979323846

// ---------------------------------------------------------------------------
// f32 Wigner small-d column scale*d^l_{mp,mn}(beta), l=0..29 (zeros below
// lmin), Jacobi recurrence. Convention == expm(-(beta/2)(J+ - J-)), verified
// on-hardware r1-r3.
// ---------------------------------------------------------------------------
__device__ void wigner_colf(float beta, int mp, int mn, float scale,
                            float* out, int stride) {
  int a = mp - mn; if (a < 0) a = -a;
  int b = mp + mn; if (b < 0) b = -b;
  int lmin = (a + b) >> 1;
  for (int l = 0; l < LMAX; ++l) out[l * stride] = 0.0f;
  if (lmin >= LMAX) return;
  float sh, ch; sincosf(0.5f * beta, &sh, &ch);
  float x = ch * ch - sh * sh;
  float base = scale;
  for (int q = 0; q < a; ++q) base *= sh;
  for (int q = 0; q < b; ++q) base *= ch;
  if (mp >= mn && ((mp - mn) & 1)) base = -base;
  float K2 = 1.f;
  for (int q = 1; q <= a; ++q) K2 *= (float)(b + q) / (float)q;
  float Pm2 = 0.f, Pm1 = 1.f;
  out[lmin * stride] = base * sqrtf(K2);
  for (int s = 1; lmin + s < LMAX; ++s) {
    float Ps;
    if (s == 1) {
      Ps = (a + 1) + (a + b + 2) * 0.5f * (x - 1.f);
    } else {
      float t0 = 2.f * s + a + b;
      float c1 = 2.f * s * (s + a + b) * (t0 - 2.f);
      float c2 = (t0 - 1.f) * (t0 * (t0 - 2.f) * x + (float)(a * a - b * b));
      float c3 = 2.f * (s + a - 1.f) * (s + b - 1.f) * t0;
      Ps = (c2 * Pm1 - c3 * Pm2) / c1;
    }
    K2 *= ((float)s * (s + a + b)) / (((float)s + a) * ((float)s + b));
    out[(lmin + s) * stride] = base * sqrtf(K2) * Ps;
    Pm2 = Pm1; Pm1 = Ps;
  }
}

// ---------------------------------------------------------------------------
// K_prep (62 x 64):
//  block 0      : scwF1/scwF2[nn][pair] = wqn[21+nn] * sum_p w[pair,p] e^{+2pi i n p/6}
//                 (scwF2 additionally x pi for the synth->fft bridge)
//  block 1      : dkw[l][nn] = (2l+1) * d^l_{nn-8,0}(pi/160)
//  blocks 2..61 : D0T[M][l][j] = wq[j] * d^l_{M-29,0}(beta_j)
// ---------------------------------------------------------------------------
__global__ __launch_bounds__(64)
void k_prep(const float* __restrict__ wc, const float* __restrict__ wd,
            float2* __restrict__ scwF1, float2* __restrict__ scwF2,
            float* __restrict__ dkw, float* __restrict__ D0T) {
  int bi = blockIdx.x, t = threadIdx.x;
  if (bi == 0) {
    __shared__ float swq[NBG];
    __shared__ float2 swqn[NT];
    if (t < NBG) {
      float s = 0.f;
      for (int k = 0; k < 30; ++k) {
        int r = ((2 * t + 1) * (2 * k + 1)) % 240;
        s += sinf(2.f * PI_F * r / 240.f) / (float)(2 * k + 1);
      }
      swq[t] = (2.f / 30.f) * sinf(PI_F * (2 * t + 1) / 120.f) * s;
    }
    __syncthreads();
    if (t < NT) {
      int n = t - NOFF;
      float re = 0.f, im = 0.f;
      for (int g = 0; g < NBG; ++g) {
        int k = ((n * g) % NBG + NBG) % NBG;
        float sn, cs; sincosf(2.f * PI_F * k / 60.f, &sn, &cs);
        re += swq[g] * cs; im += swq[g] * sn;
      }
      swqn[t] = make_float2(re, im);
    }
    __syncthreads();
    for (int idx = t; idx < NT * NPAIR; idx += 64) {
      int nn = idx / NPAIR, pair = idx - nn * NPAIR, n = nn - NOFF;
      float re1 = 0, im1 = 0, re2 = 0, im2 = 0;
      for (int p = 0; p < 6; ++p) {
        int k = ((n * p) % 6 + 6) % 6;
        float sn, cs; sincosf(2.f * PI_F * k / 6.f, &sn, &cs);
        float a1 = wc[pair * 6 + p], a2 = wd[pair * 6 + p];
        re1 += a1 * cs; im1 += a1 * sn;
        re2 += a2 * cs; im2 += a2 * sn;
      }
      float2 w = swqn[nn];
      scwF1[idx] = make_float2(w.x * re1 - w.y * im1, w.x * im1 + w.y * re1);
      scwF2[idx] = make_float2(PI_F * (w.x * re2 - w.y * im2),
                               PI_F * (w.x * im2 + w.y * re2));
    }
  } else if (bi == 1) {
    if (t < NT) {
      wigner_colf(PI_F / 160.f, t - NOFF, 0, 1.f, dkw + t, NT);
      for (int l = 0; l < LMAX; ++l) dkw[l * NT + t] *= (float)(2 * l + 1);
    }
  } else {
    int j = bi - 2;
    if (t < MWC) {
      float s = 0.f;
      for (int k = 0; k < 30; ++k) {
        int r = ((2 * j + 1) * (2 * k + 1)) % 240;
        s += sinf(2.f * PI_F * r / 240.f) / (float)(2 * k + 1);
      }
      float wqj = (2.f / 30.f) * sinf(PI_F * (2 * j + 1) / 120.f) * s;
      wigner_colf(PI_F * (2 * j + 1) / 120.f, t - CTR, 0, wqj,
                  D0T + (size_t)t * LMAX * NBG + j, NBG);
    }
  }
}

// ---------------------------------------------------------------------------
// K_dft1 (grid 120 = j*2+half, 256 thr): alpha-DFT of x1 rows.
// xfT[M][j][bi] = (2pi/60) sum_a x1[bi][j][a] e^{-2pi i (M-29) a/60}
// ---------------------------------------------------------------------------
__global__ __launch_bounds__(256)
void k_dft1(const float* __restrict__ x1, float2* __restrict__ xfT) {
  __shared__ float xr[16][NBG];
  __shared__ float twc[NBG], tws[NBG];
  __shared__ float2 xo[MWC][17];          // padded stride 17 (bank-safe)
  int j = blockIdx.x >> 1, h = blockIdx.x & 1;
  int t = threadIdx.x;
  for (int q = t; q < 16 * NBG; q += 256) {
    int bl = q / NBG, a = q - bl * NBG;
    xr[bl][a] = x1[((size_t)(h * 16 + bl) * NBG + j) * NBG + a];
  }
  if (t < NBG) {
    float s, c; sincosf(-2.f * PI_F * t / 60.f, &s, &c);
    twc[t] = c; tws[t] = s;
  }
  __syncthreads();
  for (int q = t; q < 16 * MWC; q += 256) {
    int bl = q / MWC, M = q - bl * MWC, mm = M - CTR;
    float re = 0.f, im = 0.f; int k = 0;
    for (int a = 0; a < NBG; ++a) {
      re += xr[bl][a] * twc[k]; im += xr[bl][a] * tws[k];
      k += mm; if (k >= NBG) k -= NBG; if (k < 0) k += NBG;
    }
    const float sc = 2.f * PI_F / 60.f;
    xo[M][bl] = make_float2(re * sc, im * sc);
  }
  __syncthreads();
  for (int q = t; q < MWC * 16; q += 256) {
    int M = q / 16, bl = q - M * 16;
    xfT[((size_t)M * NBG + j) * 32 + h * 16 + bl] = xo[M][bl];
  }
}

// ---------------------------------------------------------------------------
// K_ana1 (grid 59 M, 256 thr): X21[M][l][i][b] = sum_j D0T[M,l,j]*xfT[M,j,b*2+i]
// ---------------------------------------------------------------------------
__global__ __launch_bounds__(256)
void k_ana1(const float2* __restrict__ xfT, const float* __restrict__ D0T,
            float2* __restrict__ X21) {
  __shared__ float2 sxf[NBG][32];   // 15.36 KB
  __shared__ float  sD[LMAX][NBG];  //  7.2 KB
  int M = blockIdx.x, t = threadIdx.x;
  for (int q = t; q < NBG * 32; q += 256) ((float2*)sxf)[q] = xfT[(size_t)M * NBG * 32 + q];
  for (int q = t; q < LMAX * NBG; q += 256) ((float*)sD)[q] = D0T[(size_t)M * LMAX * NBG + q];
  __syncthreads();
  for (int q = t; q < LMAX * 32; q += 256) {   // q = (l*2+i)*16+b
    int l = q >> 5, i = (q >> 4) & 1, b = q & 15;
    float re = 0.f, im = 0.f;
    for (int j = 0; j < NBG; ++j) {
      float w = sD[l][j];
      float2 v = sxf[j][b * 2 + i];
      re += w * v.x; im += w * v.y;
    }
    X21[(size_t)M * LMAX * 32 + q] = make_float2(re, im);
  }
}

// ---------------------------------------------------------------------------
// K_core<CI,CO>: grid 1800 = j*30+mg (M = 2*mg+Mi), 256 thr.
//  phase1: 34 columns (Mi,nn): Wigner recurrence -> sg[l][col] = d * dkw[l,nn]
//  phase2: sC[Mi][l][pair] = sum_nn sg * scwF[nn][pair]   (K=17)
//  phase3 (CO=10): T1[j][M][u] = sum_{i,l} X21[M,l,i,bb]*sC[Mi,l,i*10+o]
//  phase3 (CO=2) : 4-way l-split + LDS reduce -> T2[j][M][u]
// ---------------------------------------------------------------------------
template <int CI, int CO>
__global__ __launch_bounds__(256)
void k_core(const float2* __restrict__ X2, const float* __restrict__ dkw,
            const float2* __restrict__ scwF, float2* __restrict__ T) {
  __shared__ float  sg[LMAX][36];        // 34 cols + pad
  __shared__ float2 sC[2 * LMAX * NPAIR];
  __shared__ float2 scw[NT * NPAIR];
  __shared__ float  sdk[LMAX * NT];
  __shared__ float2 sRed[256];
  int t = threadIdx.x;
  int j = blockIdx.x / 30, mg = blockIdx.x - 30 * j;
  int Mbase = mg * 2;

  for (int q = t; q < NT * NPAIR; q += 256) scw[q] = scwF[q];
  for (int q = t; q < LMAX * NT; q += 256) sdk[q] = dkw[q];

  if (t < 34) {
    int Mi = t / NT, nn = t - Mi * NT;
    int M = Mbase + Mi;
    if (M < MWC) {
      int mp = M - CTR, mn = nn - NOFF;
      wigner_colf((float)(PI_D * (2.0 * j + 1.0) / 120.0), mp, mn, 1.f,
                  &sg[0][t], 36);
      for (int l = 0; l < LMAX; ++l) sg[l][t] *= sdk[l * NT + nn];
    } else {
      for (int l = 0; l < LMAX; ++l) sg[l][t] = 0.f;
    }
  }
  __syncthreads();

  // phase 2: q = Mi*600 + l*20 + pair
  for (int q = t; q < 2 * LMAX * NPAIR; q += 256) {
    int Mi = q / (LMAX * NPAIR);
    int r = q - Mi * LMAX * NPAIR;
    int l = r / NPAIR, pair = r - l * NPAIR;
    float cre = 0.f, cim = 0.f;
#pragma unroll
    for (int nn = 0; nn < NT; ++nn) {
      float g = sg[l][Mi * NT + nn];
      float2 c = scw[nn * NPAIR + pair];
      cre += g * c.x; cim += g * c.y;
    }
    sC[q] = make_float2(cre, cim);
  }
  __syncthreads();

  if constexpr (CO == 10) {
    for (int q = t; q < 2 * 160; q += 256) {
      int Mi = q / 160, u = q - Mi * 160;
      int M = Mbase + Mi;
      if (M >= MWC) continue;
      int bb = u / 10, o = u - 10 * bb;
      float tre = 0.f, tim = 0.f;
      for (int i = 0; i < CI; ++i) {
        const float2* xp = X2 + (size_t)(M * LMAX) * 32 + i * 16 + bb;
        const float2* cp = sC + Mi * LMAX * NPAIR + i * 10 + o;
#pragma unroll
        for (int l = 0; l < LMAX; ++l) {
          float2 xv = xp[l * 32];
          float2 cv = cp[l * NPAIR];
          tre += xv.x * cv.x - xv.y * cv.y;
          tim += xv.x * cv.y + xv.y * cv.x;
        }
      }
      T[((size_t)j * MWC + M) * 160 + u] = make_float2(tre, tim);
    }
  } else {
    // CO == 2: 64 outputs (Mi,u), 4-way l-split
    int sub = t >> 6, idx = t & 63;
    int Mi = idx >> 5, u = idx & 31;
    int M = Mbase + Mi;
    int bb = u >> 1, o = u & 1;
    float tre = 0.f, tim = 0.f;
    if (M < MWC) {
      for (int i = 0; i < CI; ++i) {
        const float2* xp = X2 + (size_t)(M * LMAX) * 160 + bb * 10 + i;
        const float2* cp = sC + Mi * LMAX * NPAIR + i * 2 + o;
        for (int l = sub; l < LMAX; l += 4) {
          float2 xv = xp[l * 160];
          float2 cv = cp[l * NPAIR];
          tre += xv.x * cv.x - xv.y * cv.y;
          tim += xv.x * cv.y + xv.y * cv.x;
        }
      }
    }
    sRed[t] = make_float2(tre, tim);
    __syncthreads();
    if (t < 64 && M < MWC) {
      float2 a0 = sRed[t], a1 = sRed[t + 64], a2 = sRed[t + 128], a3 = sRed[t + 192];
      T[((size_t)j * MWC + M) * 32 + u] =
          make_float2(a0.x + a1.x + a2.x + a3.x, a0.y + a1.y + a2.y + a3.y);
    }
  }
}

// ---------------------------------------------------------------------------
// K_ana2 (grid 59*4 = M*4+q4, 256 thr): stage-2 analysis with fused bridge
//   xf2[j][u] = T1[j][M][u] + conj(T1[j][58-M][u])   (pi folded into scwF2)
//   X22[M][l][b][i] = sum_j D0T[M,l,j] * xf2[j][b*10+i]
// ---------------------------------------------------------------------------
__global__ __launch_bounds__(256)
void k_ana2(const float2* __restrict__ T1, const float* __restrict__ D0T,
            float2* __restrict__ X22) {
  __shared__ float2 sxf[NBG][40];   // 19.2 KB
  __shared__ float  sD[LMAX][NBG];  //  7.2 KB
  int M = blockIdx.x >> 2, q4 = blockIdx.x & 3;
  int u0 = q4 * 40, t = threadIdx.x;
  for (int q = t; q < NBG * 40; q += 256) {
    int j = q / 40, uq = q - j * 40;
    float2 v1 = T1[((size_t)j * MWC + M) * 160 + u0 + uq];
    float2 v2 = T1[((size_t)j * MWC + (58 - M)) * 160 + u0 + uq];
    sxf[j][uq] = make_float2(v1.x + v2.x, v1.y - v2.y);
  }
  for (int q = t; q < LMAX * NBG; q += 256) ((float*)sD)[q] = D0T[(size_t)M * LMAX * NBG + q];
  __syncthreads();
  for (int q = t; q < LMAX * 40; q += 256) {  // q = l*40 + w
    int l = q / 40, w = q - l * 40;
    float re = 0.f, im = 0.f;
    for (int j = 0; j < NBG; ++j) {
      float d = sD[l][j];
      float2 v = sxf[j][w];
      re += d * v.x; im += d * v.y;
    }
    X22[(size_t)(M * LMAX + l) * 160 + u0 + w] = make_float2(re, im);
  }
}

// ---------------------------------------------------------------------------
// K_synth2 (grid 60 j, 256 thr): out[u][j][a] = Re sum_M T2[j][M][u] e^{+2pi i(M-29)a/60}
// ---------------------------------------------------------------------------
__global__ __launch_bounds__(256)
void k_synth2(const float2* __restrict__ T2, float* __restrict__ out) {
  __shared__ float2 sT[MWC][32];    // 15.1 KB
  __shared__ float twc[NBG], tws[NBG];
  int j = blockIdx.x, t = threadIdx.x;
  for (int q = t; q < MWC * 32; q += 256) ((float2*)sT)[q] = T2[(size_t)j * MWC * 32 + q];
  if (t < NBG) {
    float s, c; sincosf(2.f * PI_F * t / 60.f, &s, &c);
    twc[t] = c; tws[t] = s;
  }
  __syncthreads();
  for (int q = t; q < 32 * NBG; q += 256) {
    int u = q / NBG, a = q - u * NBG;
    int k = (31 * a) % NBG;          // (-29*a) mod 60
    float acc = 0.f;
    for (int M = 0; M < MWC; ++M) {
      float2 v = sT[M][u];
      acc += v.x * twc[k] - v.y * tws[k];
      k += a; if (k >= NBG) k -= NBG;
    }
    out[((size_t)u * NBG + j) * NBG + a] = acc;
  }
}

// ---------------------------------------------------------------------------
extern "C" void kernel_launch(void* const* d_in, const int* in_sizes, int n_in,
                              void* d_out, int out_size, void* d_ws, size_t ws_size,
                              hipStream_t stream) {
  const float* x1       = (const float*)d_in[0];
  const float* w_conv   = (const float*)d_in[1];
  const float* w_deconv = (const float*)d_in[2];
  float* out = (float*)d_out;
  char* ws = (char*)d_ws;

  float2* scwF1 = (float2*)(ws + 0);        // 17*20 c64 = 2720
  float2* scwF2 = (float2*)(ws + 4096);     // 2720
  float*  dkw   = (float*) (ws + 8192);     // 30*17 f32 = 2040
  float*  D0T   = (float*) (ws + 16384);    // 59*30*60 f32 = 424800
  float2* xfT   = (float2*)(ws + 442368);   // 59*60*32 c64 = 906240
  float2* X21   = (float2*)(ws + 1349632);  // 59*30*2*16 c64 = 453120
  float2* T1    = (float2*)(ws + 1803264);  // 60*59*160 c64 = 4531200
  float2* X22   = (float2*)(ws + 6334464);  // 59*30*160 c64 = 2265600
  float2* T2    = (float2*)(ws + 8600064);  // 60*59*32 c64 = 906240
  // total 9506304 B (< 9.56 MB used in r1/r2, proven available)

  k_prep<<<NBG + 2, 64, 0, stream>>>(w_conv, w_deconv, scwF1, scwF2, dkw, D0T);
  k_dft1<<<NBG * 2, 256, 0, stream>>>(x1, xfT);
  k_ana1<<<MWC, 256, 0, stream>>>(xfT, D0T, X21);
  k_core<2, 10><<<NBG * 30, 256, 0, stream>>>(X21, dkw, scwF1, T1);
  k_ana2<<<MWC * 4, 256, 0, stream>>>(T1, D0T, X22);
  k_core<10, 2><<<NBG * 30, 256, 0, stream>>>(X22, dkw, scwF2, T2);
  k_synth2<<<NBG, 256, 0, stream>>>(T2, out);
}

// Round 6
// 116.270 us; speedup vs baseline: 3.1029x; 1.6689x over previous
//
#include <hip/hip_runtime.h>
#include <hip/hip_fp16.h>

#define NBG   60
#define LMAX  30
#define MWC   59
#define CTR   29
#define NPAIR 20
#define NT    11          // |n| <= 5 (dk ~ J_n(l*beta), J_6(0.57) ~ 8e-7)
#define NTP   12          // padded
#define NOFF  5
#define PI_F  3.14159265358979323846f
#define PI_D  3.14159265358979323846

// ---------------------------------------------------------------------------
// f32 Wigner small-d column scale*d^l_{mp,mn}(beta), l=0..29 (zeros below
// lmin), Jacobi recurrence. Convention == expm(-(beta/2)(J+ - J-)), verified
// on-hardware r1-r4.
// ---------------------------------------------------------------------------
__device__ void wigner_colf(float beta, int mp, int mn, float scale,
                            float* out, int stride) {
  int a = mp - mn; if (a < 0) a = -a;
  int b = mp + mn; if (b < 0) b = -b;
  int lmin = (a + b) >> 1;
  for (int l = 0; l < LMAX; ++l) out[l * stride] = 0.0f;
  if (lmin >= LMAX) return;
  float sh, ch; sincosf(0.5f * beta, &sh, &ch);
  float x = ch * ch - sh * sh;
  float base = scale;
  for (int q = 0; q < a; ++q) base *= sh;
  for (int q = 0; q < b; ++q) base *= ch;
  if (mp >= mn && ((mp - mn) & 1)) base = -base;
  float K2 = 1.f;
  for (int q = 1; q <= a; ++q) K2 *= (float)(b + q) / (float)q;
  float Pm2 = 0.f, Pm1 = 1.f;
  out[lmin * stride] = base * sqrtf(K2);
  for (int s = 1; lmin + s < LMAX; ++s) {
    float Ps;
    if (s == 1) {
      Ps = (a + 1) + (a + b + 2) * 0.5f * (x - 1.f);
    } else {
      float t0 = 2.f * s + a + b;
      float c1 = 2.f * s * (s + a + b) * (t0 - 2.f);
      float c2 = (t0 - 1.f) * (t0 * (t0 - 2.f) * x + (float)(a * a - b * b));
      float c3 = 2.f * (s + a - 1.f) * (s + b - 1.f) * t0;
      Ps = (c2 * Pm1 - c3 * Pm2) / c1;
    }
    K2 *= ((float)s * (s + a + b)) / (((float)s + a) * ((float)s + b));
    out[(lmin + s) * stride] = base * sqrtf(K2) * Ps;
    Pm2 = Pm1; Pm1 = Ps;
  }
}

__device__ __forceinline__ float quad_w(int j) {
  float s = 0.f;
  for (int k = 0; k < 30; ++k) {
    int r = ((2 * j + 1) * (2 * k + 1)) % 240;
    s += sinf(2.f * PI_F * r / 240.f) / (float)(2 * k + 1);
  }
  return (2.f / 30.f) * sinf(PI_F * (2 * j + 1) / 120.f) * s;
}

// ---------------------------------------------------------------------------
// K_prep (61 x 64):
//  bi 0      : scwF1/scwF2[nn][pair] = wqn[n] * sum_p w[pair,p] e^{+2pi i n p/6}
//              (scwF2 additionally x pi for the synth->fft bridge)
//  bi 1      : dkw[l][nn] = (2l+1) * d^l_{nn-5,0}(pi/160)   ([30][12] padded)
//  bi 2..60  : M = bi-2; lane j: D0T[M][l][j] = wq[j]*d^l_{M-29,0}(beta_j)
// ---------------------------------------------------------------------------
__global__ __launch_bounds__(64)
void k_prep(const float* __restrict__ wc, const float* __restrict__ wd,
            float2* __restrict__ scwF1, float2* __restrict__ scwF2,
            float* __restrict__ dkw, float* __restrict__ D0T) {
  int bi = blockIdx.x, t = threadIdx.x;
  if (bi == 0) {
    __shared__ float swq[NBG];
    __shared__ float2 swqn[NT];
    if (t < NBG) swq[t] = quad_w(t);
    __syncthreads();
    if (t < NT) {
      int n = t - NOFF;
      float re = 0.f, im = 0.f;
      for (int g = 0; g < NBG; ++g) {
        int k = ((n * g) % NBG + NBG) % NBG;
        float sn, cs; sincosf(2.f * PI_F * k / 60.f, &sn, &cs);
        re += swq[g] * cs; im += swq[g] * sn;
      }
      swqn[t] = make_float2(re, im);
    }
    __syncthreads();
    for (int idx = t; idx < NT * NPAIR; idx += 64) {
      int nn = idx / NPAIR, pair = idx - nn * NPAIR, n = nn - NOFF;
      float re1 = 0, im1 = 0, re2 = 0, im2 = 0;
      for (int p = 0; p < 6; ++p) {
        int k = ((n * p) % 6 + 6) % 6;
        float sn, cs; sincosf(2.f * PI_F * k / 6.f, &sn, &cs);
        float a1 = wc[pair * 6 + p], a2 = wd[pair * 6 + p];
        re1 += a1 * cs; im1 += a1 * sn;
        re2 += a2 * cs; im2 += a2 * sn;
      }
      float2 w = swqn[nn];
      scwF1[idx] = make_float2(w.x * re1 - w.y * im1, w.x * im1 + w.y * re1);
      scwF2[idx] = make_float2(PI_F * (w.x * re2 - w.y * im2),
                               PI_F * (w.x * im2 + w.y * re2));
    }
  } else if (bi == 1) {
    if (t < NT) {
      wigner_colf(PI_F / 160.f, t - NOFF, 0, 1.f, dkw + t, NTP);
      for (int l = 0; l < LMAX; ++l) dkw[l * NTP + t] *= (float)(2 * l + 1);
    }
  } else {
    int M = bi - 2;
    if (t < NBG) {
      float wqj = quad_w(t);
      wigner_colf(PI_F * (2 * t + 1) / 120.f, M - CTR, 0, wqj,
                  D0T + (size_t)M * LMAX * NBG + t, NBG);
    }
  }
}

// ---------------------------------------------------------------------------
// K_sgd (120 = j*2+Mq, 256 thr): one thread per (Mi, nn) column.
//  sgd[j][M][l][nn] = d^l_{M-29, nn-5}(beta_j) * dkw[l][nn],  M = 0..29 only
//  (M >= 30 reconstructed in cores via d_{-m,-n} symmetry).
// ---------------------------------------------------------------------------
__global__ __launch_bounds__(256)
void k_sgd(const float* __restrict__ dkw, float* __restrict__ sgd) {
  __shared__ float buf[15 * LMAX * NTP];   // 21600 B
  int j = blockIdx.x >> 1, Mq = blockIdx.x & 1;
  int t = threadIdx.x;
  if (t < 15 * NT) {
    int Mi = t / NT, nn = t - Mi * NT;
    int mp = Mq * 15 + Mi - CTR, mn = nn - NOFF;
    wigner_colf(PI_F * (2 * j + 1) / 120.f, mp, mn, 1.f,
                &buf[Mi * LMAX * NTP + nn], NTP);
  }
  __syncthreads();
  size_t base = (size_t)(j * 30 + Mq * 15) * LMAX * NTP;
  for (int q = t; q < 15 * LMAX * NTP; q += 256) {
    int r = q % (LMAX * NTP), l = r / NTP, nn = r - l * NTP;
    float v = (nn < NT) ? buf[q] * dkw[l * NTP + nn] : 0.f;
    sgd[base + q] = v;
  }
}

// ---------------------------------------------------------------------------
// K_dft1 (240 = j*4+qh, 256 thr): alpha-DFT of 8 x1 rows.
// xfT[M][j][rb] = (2pi/60) sum_a x1[rb][j][a] e^{-2pi i (M-29) a/60}
// ---------------------------------------------------------------------------
__global__ __launch_bounds__(256)
void k_dft1(const float* __restrict__ x1, float2* __restrict__ xfT) {
  __shared__ float xr[8][NBG];
  __shared__ float twc[NBG], tws[NBG];
  __shared__ float2 xo[MWC][9];
  int j = blockIdx.x >> 2, qh = blockIdx.x & 3;
  int t = threadIdx.x;
  for (int q = t; q < 8 * NBG; q += 256) {
    int bl = q / NBG, a = q - bl * NBG;
    xr[bl][a] = x1[((size_t)(qh * 8 + bl) * NBG + j) * NBG + a];
  }
  if (t < NBG) {
    float s, c; sincosf(-2.f * PI_F * t / 60.f, &s, &c);
    twc[t] = c; tws[t] = s;
  }
  __syncthreads();
  for (int q = t; q < 8 * MWC; q += 256) {
    int bl = q / MWC, M = q - bl * MWC, mm = M - CTR;
    float re = 0.f, im = 0.f; int k = 0;
    for (int a = 0; a < NBG; ++a) {
      re += xr[bl][a] * twc[k]; im += xr[bl][a] * tws[k];
      k += mm; if (k >= NBG) k -= NBG; if (k < 0) k += NBG;
    }
    const float sc = 2.f * PI_F / 60.f;
    xo[M][bl] = make_float2(re * sc, im * sc);
  }
  __syncthreads();
  for (int q = t; q < MWC * 8; q += 256) {
    int M = q / 8, bl = q - M * 8;
    xfT[((size_t)M * NBG + j) * 32 + qh * 8 + bl] = xo[M][bl];
  }
}

// ---------------------------------------------------------------------------
// K_ana1 (236 = M*4+lq, 256 thr): X21[M][l][i][b] = sum_j D0T[M,l,j]*xfT[M,j,b*2+i]
// ---------------------------------------------------------------------------
__global__ __launch_bounds__(256)
void k_ana1(const float2* __restrict__ xfT, const float* __restrict__ D0T,
            float2* __restrict__ X21) {
  __shared__ float2 sxf[NBG][32];   // 15360 B
  __shared__ float  sD[8][NBG];     //  1920 B
  int M = blockIdx.x >> 2, lq = blockIdx.x & 3;
  int t = threadIdx.x;
  for (int q = t; q < NBG * 32; q += 256) ((float2*)sxf)[q] = xfT[(size_t)M * NBG * 32 + q];
  for (int q = t; q < 8 * NBG; q += 256) {
    int ll = q / NBG, jj = q - ll * NBG, l = lq * 8 + ll;
    sD[ll][jj] = (l < LMAX) ? D0T[((size_t)M * LMAX + l) * NBG + jj] : 0.f;
  }
  __syncthreads();
  int ll = t >> 5, w = t & 31, i = w >> 4, b = w & 15;
  int l = lq * 8 + ll;
  if (l < LMAX) {
    float re = 0.f, im = 0.f;
    for (int jj = 0; jj < NBG; ++jj) {
      float d = sD[ll][jj];
      float2 v = sxf[jj][b * 2 + i];
      re += d * v.x; im += d * v.y;
    }
    X21[(size_t)M * LMAX * 32 + l * 32 + w] = make_float2(re, im);
  }
}

// ---------------------------------------------------------------------------
// K_core<CI,CO> (1800 = j*30+mg, 256 thr): M = 2mg, 2mg+1.  j = 0..59!
//  stage : sg[Mi][l][nn] from sgd (mirror+sign for M>=30)
//  phase2: sC[Mi][l][pair] = sum_nn sg * scwF[nn][pair]   (K=11)
//  phase3 CO=10: T1h[j][M][u] = half2( sum_{i,l} X21*sC )
//  phase3 CO=2 : 4-way l-split + LDS reduce -> T2[j][M][u] (float2)
// ---------------------------------------------------------------------------
template <int CI, int CO>
__global__ __launch_bounds__(256)
void k_core(const float2* __restrict__ X2, const float* __restrict__ sgd,
            const float2* __restrict__ scwF, void* __restrict__ T) {
  __shared__ float  sg[2][LMAX][NTP];     // 2880 B
  __shared__ float2 scw[NT * NPAIR];      // 1760 B
  __shared__ float2 sC[2][LMAX][NPAIR];   // 9600 B
  __shared__ float2 sRed[256];
  int t = threadIdx.x;
  int j = blockIdx.x / 30, mg = blockIdx.x - 30 * j;
  int Mbase = mg * 2;

  for (int q = t; q < NT * NPAIR; q += 256) scw[q] = scwF[q];
  for (int q = t; q < 2 * LMAX * NTP; q += 256) {
    int Mi = q / (LMAX * NTP), r = q - Mi * LMAX * NTP;
    int l = r / NTP, nn = r - l * NTP;
    int M = Mbase + Mi;
    float v = 0.f;
    if (M < MWC && nn < NT) {
      if (M < 30) {
        v = sgd[(size_t)(j * 30 + M) * LMAX * NTP + r];
      } else {
        v = sgd[(size_t)(j * 30 + 58 - M) * LMAX * NTP + l * NTP + (10 - nn)];
        if (!(M & 1)) v = -v;   // sign (-1)^(M-29)
      }
    }
    ((float*)sg)[q] = v;
  }
  __syncthreads();

  for (int q = t; q < 2 * LMAX * NPAIR; q += 256) {
    int Mi = q / (LMAX * NPAIR), r = q - Mi * LMAX * NPAIR;
    int l = r / NPAIR, pair = r - l * NPAIR;
    float cre = 0.f, cim = 0.f;
#pragma unroll
    for (int nn = 0; nn < NT; ++nn) {
      float g = sg[Mi][l][nn];
      float2 c = scw[nn * NPAIR + pair];
      cre += g * c.x; cim += g * c.y;
    }
    ((float2*)sC)[q] = make_float2(cre, cim);
  }
  __syncthreads();

  if constexpr (CO == 10) {
    __half2* Th = (__half2*)T;
    for (int q = t; q < 2 * 160; q += 256) {
      int Mi = q / 160, u = q - Mi * 160;
      int M = Mbase + Mi;
      if (M >= MWC) continue;
      int bb = u / 10, o = u - 10 * bb;
      float tre = 0.f, tim = 0.f;
#pragma unroll
      for (int l = 0; l < LMAX; ++l) {
#pragma unroll
        for (int i = 0; i < CI; ++i) {
          float2 xv = X2[((size_t)M * LMAX + l) * 32 + i * 16 + bb];
          float2 cv = sC[Mi][l][i * 10 + o];
          tre += xv.x * cv.x - xv.y * cv.y;
          tim += xv.x * cv.y + xv.y * cv.x;
        }
      }
      Th[((size_t)j * MWC + M) * 160 + u] = __floats2half2_rn(tre, tim);
    }
  } else {
    float2* Tf = (float2*)T;
    int sub = t >> 6, idx = t & 63;
    int Mi = idx >> 5, u = idx & 31;
    int M = Mbase + Mi;
    int bb = u >> 1, o = u & 1;
    float tre = 0.f, tim = 0.f;
    if (M < MWC) {
      for (int l = sub; l < LMAX; l += 4) {
#pragma unroll
        for (int i = 0; i < CI; ++i) {
          float2 xv = X2[((size_t)M * LMAX + l) * 160 + bb * 10 + i];
          float2 cv = sC[Mi][l][i * 2 + o];
          tre += xv.x * cv.x - xv.y * cv.y;
          tim += xv.x * cv.y + xv.y * cv.x;
        }
      }
    }
    sRed[t] = make_float2(tre, tim);
    __syncthreads();
    if (t < 64 && M < MWC) {
      float2 a0 = sRed[t], a1 = sRed[t + 64], a2 = sRed[t + 128], a3 = sRed[t + 192];
      Tf[((size_t)j * MWC + M) * 32 + u] =
          make_float2(a0.x + a1.x + a2.x + a3.x, a0.y + a1.y + a2.y + a3.y);
    }
  }
}

// ---------------------------------------------------------------------------
// K_ana2 (236 = M*4+q4, 256 thr): stage-2 analysis with fused synth/fft bridge
//   xf2[j][u] = T1[j][M][u] + conj(T1[j][58-M][u])   (pi folded into scwF2)
//   X22[M][l][u] = sum_j D0T[M,l,j] * xf2[j][u]
// ---------------------------------------------------------------------------
__global__ __launch_bounds__(256)
void k_ana2(const __half2* __restrict__ T1, const float* __restrict__ D0T,
            float2* __restrict__ X22) {
  __shared__ float2 sxf[NBG][40];   // 19200 B
  __shared__ float  sD[LMAX][NBG];  //  7200 B
  int M = blockIdx.x >> 2, q4 = blockIdx.x & 3;
  int u0 = q4 * 40, t = threadIdx.x;
  for (int q = t; q < NBG * 40; q += 256) {
    int jj = q / 40, uq = q - jj * 40;
    float2 v1 = __half22float2(T1[((size_t)jj * MWC + M) * 160 + u0 + uq]);
    float2 v2 = __half22float2(T1[((size_t)jj * MWC + (58 - M)) * 160 + u0 + uq]);
    sxf[jj][uq] = make_float2(v1.x + v2.x, v1.y - v2.y);
  }
  for (int q = t; q < LMAX * NBG; q += 256) ((float*)sD)[q] = D0T[(size_t)M * LMAX * NBG + q];
  __syncthreads();
  for (int q = t; q < LMAX * 40; q += 256) {
    int l = q / 40, w = q - l * 40;
    float re = 0.f, im = 0.f;
    for (int jj = 0; jj < NBG; ++jj) {
      float d = sD[l][jj];
      float2 v = sxf[jj][w];
      re += d * v.x; im += d * v.y;
    }
    X22[((size_t)M * LMAX + l) * 160 + u0 + w] = make_float2(re, im);
  }
}

// ---------------------------------------------------------------------------
// K_synth2 (120 = j*2+uh, 256 thr): out[u][j][a] = Re sum_M T2[j][M][u] e^{+2pi i(M-29)a/60}
// ---------------------------------------------------------------------------
__global__ __launch_bounds__(256)
void k_synth2(const float2* __restrict__ T2, float* __restrict__ out) {
  __shared__ float2 sT[MWC][16];    // 7552 B
  __shared__ float twc[NBG], tws[NBG];
  int j = blockIdx.x >> 1, uh = blockIdx.x & 1;
  int u0 = uh * 16, t = threadIdx.x;
  for (int q = t; q < MWC * 16; q += 256) {
    int M = q / 16, uu = q - M * 16;
    sT[M][uu] = T2[((size_t)j * MWC + M) * 32 + u0 + uu];
  }
  if (t < NBG) {
    float s, c; sincosf(2.f * PI_F * t / 60.f, &s, &c);
    twc[t] = c; tws[t] = s;
  }
  __syncthreads();
  for (int q = t; q < 16 * NBG; q += 256) {
    int uu = q / NBG, a = q - uu * NBG;
    int k = (31 * a) % NBG;          // (-29*a) mod 60
    float acc = 0.f;
    for (int M = 0; M < MWC; ++M) {
      float2 v = sT[M][uu];
      acc += v.x * twc[k] - v.y * tws[k];
      k += a; if (k >= NBG) k -= NBG;
    }
    out[((size_t)(u0 + uu) * NBG + j) * NBG + a] = acc;
  }
}

// ---------------------------------------------------------------------------
extern "C" void kernel_launch(void* const* d_in, const int* in_sizes, int n_in,
                              void* d_out, int out_size, void* d_ws, size_t ws_size,
                              hipStream_t stream) {
  const float* x1       = (const float*)d_in[0];
  const float* w_conv   = (const float*)d_in[1];
  const float* w_deconv = (const float*)d_in[2];
  float* out = (float*)d_out;
  char* ws = (char*)d_ws;

  // layout (peak 8.01 MB < 9.56 MB proven):
  float2*  scwF1 = (float2*) (ws + 0);        // 220 c64 = 1760
  float2*  scwF2 = (float2*) (ws + 2048);     // 1760
  float*   dkw   = (float*)  (ws + 4096);     // 30*12 f32 = 1440
  float*   D0T   = (float*)  (ws + 5632);     // 59*30*60 f32 = 424800
  float*   sgd   = (float*)  (ws + 430592);   // 60*30*360 f32 = 2592000
  char*    R1    = ws + 3022592;              // xfT (906240) then X22 (2265600)
  char*    R2    = ws + 5288192;              // T1 half2 (2265600) then T2 (906240)
  float2*  X21   = (float2*) (ws + 7553792);  // 453120 -> ends 8006912
  float2*  xfT   = (float2*) R1;
  float2*  X22   = (float2*) R1;
  __half2* T1    = (__half2*)R2;
  float2*  T2    = (float2*) R2;

  k_prep<<<61, 64, 0, stream>>>(w_conv, w_deconv, scwF1, scwF2, dkw, D0T);
  k_sgd<<<120, 256, 0, stream>>>(dkw, sgd);
  k_dft1<<<240, 256, 0, stream>>>(x1, xfT);
  k_ana1<<<236, 256, 0, stream>>>(xfT, D0T, X21);
  k_core<2, 10><<<1800, 256, 0, stream>>>(X21, sgd, scwF1, (void*)T1);
  k_ana2<<<236, 256, 0, stream>>>(T1, D0T, X22);
  k_core<10, 2><<<1800, 256, 0, stream>>>(X22, sgd, scwF2, (void*)T2);
  k_synth2<<<120, 256, 0, stream>>>(T2, out);
}

// Round 7
// 100.958 us; speedup vs baseline: 3.5735x; 1.1517x over previous
//
#include <hip/hip_runtime.h>
#include <hip/hip_fp16.h>

#define NBG   60
#define LMAX  30
#define MWC   59
#define CTR   29
#define NPAIR 20
#define NT    11          // |n| <= 5 truncation (validated r4/r6: absmax unchanged)
#define NTP   12
#define NOFF  5
#define PI_F  3.14159265358979323846f

// ---------------------------------------------------------------------------
// f32 Wigner small-d column scale*d^l_{mp,mn}(beta), Jacobi recurrence.
// Convention == expm(-(beta/2)(J+ - J-)), verified on-hardware r1-r6.
// ---------------------------------------------------------------------------
__device__ void wigner_colf(float beta, int mp, int mn, float scale,
                            float* out, int stride) {
  int a = mp - mn; if (a < 0) a = -a;
  int b = mp + mn; if (b < 0) b = -b;
  int lmin = (a + b) >> 1;
  for (int l = 0; l < LMAX; ++l) out[l * stride] = 0.0f;
  if (lmin >= LMAX) return;
  float sh, ch; sincosf(0.5f * beta, &sh, &ch);
  float x = ch * ch - sh * sh;
  float base = scale;
  for (int q = 0; q < a; ++q) base *= sh;
  for (int q = 0; q < b; ++q) base *= ch;
  if (mp >= mn && ((mp - mn) & 1)) base = -base;
  float K2 = 1.f;
  for (int q = 1; q <= a; ++q) K2 *= (float)(b + q) / (float)q;
  float Pm2 = 0.f, Pm1 = 1.f;
  out[lmin * stride] = base * sqrtf(K2);
  for (int s = 1; lmin + s < LMAX; ++s) {
    float Ps;
    if (s == 1) {
      Ps = (a + 1) + (a + b + 2) * 0.5f * (x - 1.f);
    } else {
      float t0 = 2.f * s + a + b;
      float c1 = 2.f * s * (s + a + b) * (t0 - 2.f);
      float c2 = (t0 - 1.f) * (t0 * (t0 - 2.f) * x + (float)(a * a - b * b));
      float c3 = 2.f * (s + a - 1.f) * (s + b - 1.f) * t0;
      Ps = (c2 * Pm1 - c3 * Pm2) / c1;
    }
    K2 *= ((float)s * (s + a + b)) / (((float)s + a) * ((float)s + b));
    out[(lmin + s) * stride] = base * sqrtf(K2) * Ps;
    Pm2 = Pm1; Pm1 = Ps;
  }
}

__device__ __forceinline__ float quad_w(int j) {
  float s = 0.f;
  for (int k = 0; k < 30; ++k) {
    int r = ((2 * j + 1) * (2 * k + 1)) % 240;
    s += sinf(2.f * PI_F * r / 240.f) / (float)(2 * k + 1);
  }
  return (2.f / 30.f) * sinf(PI_F * (2 * j + 1) / 120.f) * s;
}

// ---------------------------------------------------------------------------
// K1 (420 blocks x 256): all input-only work fused.
//  bi 0        : scwF1/scwF2[nn][pair]  (scwF2 x pi for the synth/fft bridge)
//  bi 1..59    : M = bi-1: D0T[M][l][j] = wq[j]*d^l_{M-29,0}(beta_j)
//  bi 60..179  : sgd[j][M][l][nn] = d^l_{M-29,nn-5}(beta_j)*(2l+1)*dk[l][nn]
//                (dk recomputed locally in spare lanes -> no dependency)
//  bi 180..419 : alpha-DFT of x1: xfT[M][j][rb]
// ---------------------------------------------------------------------------
__global__ __launch_bounds__(256)
void k1_prep(const float* __restrict__ x1,
             const float* __restrict__ wc, const float* __restrict__ wd,
             float2* __restrict__ scwF1, float2* __restrict__ scwF2,
             float* __restrict__ D0T, float* __restrict__ sgd,
             float2* __restrict__ xfT) {
  __shared__ __align__(16) char smem[23104];
  int bi = blockIdx.x, t = threadIdx.x;

  if (bi == 0) {
    float*  swq  = (float*)smem;          // 240 B
    float2* swqn = (float2*)(smem + 240); // 88 B
    if (t < NBG) swq[t] = quad_w(t);
    __syncthreads();
    if (t < NT) {
      int n = t - NOFF;
      float re = 0.f, im = 0.f;
      for (int g = 0; g < NBG; ++g) {
        int k = ((n * g) % NBG + NBG) % NBG;
        float sn, cs; sincosf(2.f * PI_F * k / 60.f, &sn, &cs);
        re += swq[g] * cs; im += swq[g] * sn;
      }
      swqn[t] = make_float2(re, im);
    }
    __syncthreads();
    if (t < NT * NPAIR) {
      int nn = t / NPAIR, pair = t - nn * NPAIR, n = nn - NOFF;
      float re1 = 0, im1 = 0, re2 = 0, im2 = 0;
      for (int p = 0; p < 6; ++p) {
        int k = ((n * p) % 6 + 6) % 6;
        float sn, cs; sincosf(2.f * PI_F * k / 6.f, &sn, &cs);
        float a1 = wc[pair * 6 + p], a2 = wd[pair * 6 + p];
        re1 += a1 * cs; im1 += a1 * sn;
        re2 += a2 * cs; im2 += a2 * sn;
      }
      float2 w = swqn[nn];
      scwF1[t] = make_float2(w.x * re1 - w.y * im1, w.x * im1 + w.y * re1);
      scwF2[t] = make_float2(PI_F * (w.x * re2 - w.y * im2),
                             PI_F * (w.x * im2 + w.y * re2));
    }
  } else if (bi < 60) {
    int M = bi - 1;
    if (t < NBG) {
      float wqj = quad_w(t);
      wigner_colf(PI_F * (2 * t + 1) / 120.f, M - CTR, 0, wqj,
                  D0T + (size_t)M * LMAX * NBG + t, NBG);
    }
  } else if (bi < 180) {
    float* buf  = (float*)smem;            // 21600 B
    float* dkwL = (float*)(smem + 21600);  //  1440 B
    int s = bi - 60, j = s >> 1, Mq = s & 1;
    if (t < 15 * NT) {
      int Mi = t / NT, nn = t - Mi * NT;
      int mp = Mq * 15 + Mi - CTR, mn = nn - NOFF;
      wigner_colf(PI_F * (2 * j + 1) / 120.f, mp, mn, 1.f,
                  &buf[Mi * LMAX * NTP + nn], NTP);
    } else if (t >= 165 && t < 165 + NT) {
      int nn = t - 165;
      wigner_colf(PI_F / 160.f, nn - NOFF, 0, 1.f, dkwL + nn, NTP);
      for (int l = 0; l < LMAX; ++l) dkwL[l * NTP + nn] *= (float)(2 * l + 1);
    }
    __syncthreads();
    size_t base = (size_t)(j * 30 + Mq * 15) * LMAX * NTP;
    for (int q = t; q < 15 * LMAX * NTP; q += 256) {
      int r = q % (LMAX * NTP), l = r / NTP, nn = r - l * NTP;
      float v = (nn < NT) ? buf[q] * dkwL[l * NTP + nn] : 0.f;
      sgd[base + q] = v;
    }
  } else {
    float*  xr  = (float*)smem;            // 8*60*4 = 1920
    float*  twc = (float*)(smem + 1920);   // 240
    float*  tws = (float*)(smem + 2160);   // 240
    float2* xo  = (float2*)(smem + 2400);  // 59*9*8 = 4248
    int s = bi - 180, j = s >> 2, qh = s & 3;
    for (int q = t; q < 8 * NBG; q += 256) {
      int bl = q / NBG, a = q - bl * NBG;
      xr[bl * NBG + a] = x1[((size_t)(qh * 8 + bl) * NBG + j) * NBG + a];
    }
    if (t < NBG) {
      float sn, cs; sincosf(-2.f * PI_F * t / 60.f, &sn, &cs);
      twc[t] = cs; tws[t] = sn;
    }
    __syncthreads();
    for (int q = t; q < 8 * MWC; q += 256) {
      int bl = q / MWC, M = q - bl * MWC, mm = M - CTR;
      const float* xp = xr + bl * NBG;
      float re = 0.f, im = 0.f; int k = 0;
      for (int a = 0; a < NBG; ++a) {
        re += xp[a] * twc[k]; im += xp[a] * tws[k];
        k += mm; if (k >= NBG) k -= NBG; if (k < 0) k += NBG;
      }
      const float sc = 2.f * PI_F / 60.f;
      xo[M * 9 + bl] = make_float2(re * sc, im * sc);
    }
    __syncthreads();
    for (int q = t; q < MWC * 8; q += 256) {
      int M = q / 8, bl = q - M * 8;
      xfT[((size_t)M * NBG + j) * 32 + qh * 8 + bl] = xo[M * 9 + bl];
    }
  }
}

// ---------------------------------------------------------------------------
// K2 ana1 (236 = M*4+lq): X21[M][l][i*16+b] = sum_j D0T[M,l,j]*xfT[M,j,b*2+i]
// ---------------------------------------------------------------------------
__global__ __launch_bounds__(256)
void k_ana1(const float2* __restrict__ xfT, const float* __restrict__ D0T,
            float2* __restrict__ X21) {
  __shared__ float2 sxf[NBG][32];
  __shared__ float  sD[8][NBG];
  int M = blockIdx.x >> 2, lq = blockIdx.x & 3;
  int t = threadIdx.x;
  for (int q = t; q < NBG * 32; q += 256) ((float2*)sxf)[q] = xfT[(size_t)M * NBG * 32 + q];
  for (int q = t; q < 8 * NBG; q += 256) {
    int ll = q / NBG, jj = q - ll * NBG, l = lq * 8 + ll;
    sD[ll][jj] = (l < LMAX) ? D0T[((size_t)M * LMAX + l) * NBG + jj] : 0.f;
  }
  __syncthreads();
  int ll = t >> 5, w = t & 31, i = w >> 4, b = w & 15;
  int l = lq * 8 + ll;
  if (l < LMAX) {
    float re = 0.f, im = 0.f;
#pragma unroll 6
    for (int jj = 0; jj < NBG; ++jj) {
      float d = sD[ll][jj];
      float2 v = sxf[jj][b * 2 + i];
      re += d * v.x; im += d * v.y;
    }
    X21[(size_t)M * LMAX * 32 + l * 32 + w] = make_float2(re, im);
  }
}

// ---------------------------------------------------------------------------
// K3 core1 (1800 = j*30+mg): M = 2mg, 2mg+1.
//  stage : sg from sgd (mirror+sign for M>=30), scw, and X21 slices -> LDS
//  phase2: sC[Mi][l][pair] = sum_nn sg*scw
//  phase3: T1h[j][M][u] = half2( sum_{i,l} sX*sC ),  all reads from LDS
// ---------------------------------------------------------------------------
__global__ __launch_bounds__(256)
void k_core1(const float2* __restrict__ X2, const float* __restrict__ sgd,
             const float2* __restrict__ scwF, __half2* __restrict__ Th) {
  __shared__ float  sg[2][LMAX][NTP];     //  2880
  __shared__ float2 scw[NT * NPAIR];      //  1760
  __shared__ float2 sC[2][LMAX][NPAIR];   //  9600
  __shared__ float2 sX[2][LMAX][32];      // 15360
  int t = threadIdx.x;
  int j = blockIdx.x / 30, mg = blockIdx.x - 30 * j;
  int Mbase = mg * 2;

  for (int q = t; q < NT * NPAIR; q += 256) scw[q] = scwF[q];
  for (int q = t; q < 2 * LMAX * 32; q += 256) {
    int Mi = q / (LMAX * 32), r = q - Mi * (LMAX * 32);
    int M = Mbase + Mi;
    ((float2*)sX)[q] = (M < MWC) ? X2[(size_t)M * LMAX * 32 + r]
                                 : make_float2(0.f, 0.f);
  }
  for (int q = t; q < 2 * LMAX * NTP; q += 256) {
    int Mi = q / (LMAX * NTP), r = q - Mi * LMAX * NTP;
    int l = r / NTP, nn = r - l * NTP;
    int M = Mbase + Mi;
    float v = 0.f;
    if (M < MWC && nn < NT) {
      if (M < 30) {
        v = sgd[(size_t)(j * 30 + M) * LMAX * NTP + r];
      } else {
        v = sgd[(size_t)(j * 30 + 58 - M) * LMAX * NTP + l * NTP + (10 - nn)];
        if (!(M & 1)) v = -v;   // (-1)^(M-29)
      }
    }
    ((float*)sg)[q] = v;
  }
  __syncthreads();

  for (int q = t; q < 2 * LMAX * NPAIR; q += 256) {
    int Mi = q / (LMAX * NPAIR), r = q - Mi * LMAX * NPAIR;
    int l = r / NPAIR, pair = r - l * NPAIR;
    float cre = 0.f, cim = 0.f;
#pragma unroll
    for (int nn = 0; nn < NT; ++nn) {
      float g = sg[Mi][l][nn];
      float2 c = scw[nn * NPAIR + pair];
      cre += g * c.x; cim += g * c.y;
    }
    ((float2*)sC)[q] = make_float2(cre, cim);
  }
  __syncthreads();

  for (int q = t; q < 2 * 160; q += 256) {
    int Mi = q / 160, u = q - Mi * 160;
    int M = Mbase + Mi;
    if (M >= MWC) continue;
    int bb = u / 10, o = u - 10 * bb;
    float tre = 0.f, tim = 0.f;
#pragma unroll 6
    for (int l = 0; l < LMAX; ++l) {
#pragma unroll
      for (int i = 0; i < 2; ++i) {
        float2 xv = sX[Mi][l][i * 16 + bb];
        float2 cv = sC[Mi][l][i * 10 + o];
        tre += xv.x * cv.x - xv.y * cv.y;
        tim += xv.x * cv.y + xv.y * cv.x;
      }
    }
    Th[((size_t)j * MWC + M) * 160 + u] = __floats2half2_rn(tre, tim);
  }
}

// ---------------------------------------------------------------------------
// K4 ana2 (236 = M*4+q4): stage-2 analysis with fused synth/fft bridge.
//   xf2[j][u] = T1[j][M][u] + conj(T1[j][58-M][u])  (pi folded into scwF2)
//   X22[M][l][i*16+b] = sum_j D0T[M,l,j] * xf2[j][b*10+i]   <- i-major layout!
// ---------------------------------------------------------------------------
__global__ __launch_bounds__(256)
void k_ana2(const __half2* __restrict__ T1, const float* __restrict__ D0T,
            float2* __restrict__ X22) {
  __shared__ float2 sxf[NBG][40];
  __shared__ float  sD[LMAX][NBG];
  int M = blockIdx.x >> 2, q4 = blockIdx.x & 3;
  int u0 = q4 * 40, t = threadIdx.x;
  for (int q = t; q < NBG * 40; q += 256) {
    int jj = q / 40, uq = q - jj * 40;
    float2 v1 = __half22float2(T1[((size_t)jj * MWC + M) * 160 + u0 + uq]);
    float2 v2 = __half22float2(T1[((size_t)jj * MWC + (58 - M)) * 160 + u0 + uq]);
    sxf[jj][uq] = make_float2(v1.x + v2.x, v1.y - v2.y);
  }
  for (int q = t; q < LMAX * NBG; q += 256) ((float*)sD)[q] = D0T[(size_t)M * LMAX * NBG + q];
  __syncthreads();
  for (int q = t; q < LMAX * 40; q += 256) {
    int l = q / 40, w = q - l * 40;
    float re = 0.f, im = 0.f;
#pragma unroll 6
    for (int jj = 0; jj < NBG; ++jj) {
      float d = sD[l][jj];
      float2 v = sxf[jj][w];
      re += d * v.x; im += d * v.y;
    }
    int uu = u0 + w;
    int p = (uu % 10) * 16 + uu / 10;   // [i][b] layout for coalesced core2 reads
    X22[((size_t)M * LMAX + l) * 160 + p] = make_float2(re, im);
  }
}

// ---------------------------------------------------------------------------
// K5 core2 (1800 = j*30+mg): 4-way l-split + LDS reduce -> T2[j][M][u]
//  X22 reads now coalesced via [i][b] layout.
// ---------------------------------------------------------------------------
__global__ __launch_bounds__(256)
void k_core2(const float2* __restrict__ X2, const float* __restrict__ sgd,
             const float2* __restrict__ scwF, float2* __restrict__ Tf) {
  __shared__ float  sg[2][LMAX][NTP];
  __shared__ float2 scw[NT * NPAIR];
  __shared__ float2 sC[2][LMAX][NPAIR];
  __shared__ float2 sRed[256];
  int t = threadIdx.x;
  int j = blockIdx.x / 30, mg = blockIdx.x - 30 * j;
  int Mbase = mg * 2;

  for (int q = t; q < NT * NPAIR; q += 256) scw[q] = scwF[q];
  for (int q = t; q < 2 * LMAX * NTP; q += 256) {
    int Mi = q / (LMAX * NTP), r = q - Mi * LMAX * NTP;
    int l = r / NTP, nn = r - l * NTP;
    int M = Mbase + Mi;
    float v = 0.f;
    if (M < MWC && nn < NT) {
      if (M < 30) {
        v = sgd[(size_t)(j * 30 + M) * LMAX * NTP + r];
      } else {
        v = sgd[(size_t)(j * 30 + 58 - M) * LMAX * NTP + l * NTP + (10 - nn)];
        if (!(M & 1)) v = -v;
      }
    }
    ((float*)sg)[q] = v;
  }
  __syncthreads();

  for (int q = t; q < 2 * LMAX * NPAIR; q += 256) {
    int Mi = q / (LMAX * NPAIR), r = q - Mi * LMAX * NPAIR;
    int l = r / NPAIR, pair = r - l * NPAIR;
    float cre = 0.f, cim = 0.f;
#pragma unroll
    for (int nn = 0; nn < NT; ++nn) {
      float g = sg[Mi][l][nn];
      float2 c = scw[nn * NPAIR + pair];
      cre += g * c.x; cim += g * c.y;
    }
    ((float2*)sC)[q] = make_float2(cre, cim);
  }
  __syncthreads();

  int sub = t >> 6, idx = t & 63;
  int Mi = idx >> 5, u = idx & 31;
  int M = Mbase + Mi;
  int bb = u >> 1, o = u & 1;
  float tre = 0.f, tim = 0.f;
  if (M < MWC) {
    for (int l = sub; l < LMAX; l += 4) {
#pragma unroll
      for (int i = 0; i < 10; ++i) {
        float2 xv = X2[((size_t)M * LMAX + l) * 160 + i * 16 + bb];
        float2 cv = sC[Mi][l][i * 2 + o];
        tre += xv.x * cv.x - xv.y * cv.y;
        tim += xv.x * cv.y + xv.y * cv.x;
      }
    }
  }
  sRed[t] = make_float2(tre, tim);
  __syncthreads();
  if (t < 64 && M < MWC) {
    float2 a0 = sRed[t], a1 = sRed[t + 64], a2 = sRed[t + 128], a3 = sRed[t + 192];
    Tf[((size_t)j * MWC + M) * 32 + u] =
        make_float2(a0.x + a1.x + a2.x + a3.x, a0.y + a1.y + a2.y + a3.y);
  }
}

// ---------------------------------------------------------------------------
// K6 synth2 (120 = j*2+uh): out[u][j][a] = Re sum_M T2[j][M][u] e^{+2pi i(M-29)a/60}
// ---------------------------------------------------------------------------
__global__ __launch_bounds__(256)
void k_synth2(const float2* __restrict__ T2, float* __restrict__ out) {
  __shared__ float2 sT[MWC][16];
  __shared__ float twc[NBG], tws[NBG];
  int j = blockIdx.x >> 1, uh = blockIdx.x & 1;
  int u0 = uh * 16, t = threadIdx.x;
  for (int q = t; q < MWC * 16; q += 256) {
    int M = q / 16, uu = q - M * 16;
    sT[M][uu] = T2[((size_t)j * MWC + M) * 32 + u0 + uu];
  }
  if (t < NBG) {
    float s, c; sincosf(2.f * PI_F * t / 60.f, &s, &c);
    twc[t] = c; tws[t] = s;
  }
  __syncthreads();
  for (int q = t; q < 16 * NBG; q += 256) {
    int uu = q / NBG, a = q - uu * NBG;
    int k = (31 * a) % NBG;          // (-29*a) mod 60
    float acc = 0.f;
#pragma unroll 4
    for (int M = 0; M < MWC; ++M) {
      float2 v = sT[M][uu];
      acc += v.x * twc[k] - v.y * tws[k];
      k += a; if (k >= NBG) k -= NBG;
    }
    out[((size_t)(u0 + uu) * NBG + j) * NBG + a] = acc;
  }
}

// ---------------------------------------------------------------------------
extern "C" void kernel_launch(void* const* d_in, const int* in_sizes, int n_in,
                              void* d_out, int out_size, void* d_ws, size_t ws_size,
                              hipStream_t stream) {
  const float* x1       = (const float*)d_in[0];
  const float* w_conv   = (const float*)d_in[1];
  const float* w_deconv = (const float*)d_in[2];
  float* out = (float*)d_out;
  char* ws = (char*)d_ws;

  // layout (peak 8.01 MB):
  float2*  scwF1 = (float2*) (ws + 0);        // 220 c64 = 1760
  float2*  scwF2 = (float2*) (ws + 2048);     // 1760
  float*   D0T   = (float*)  (ws + 4096);     // 59*30*60 f32 = 424800
  float*   sgd   = (float*)  (ws + 430080);   // 60*30*360 f32 = 2592000
  char*    R1    = ws + 3022592;              // xfT (906240) then X22 (2265600)
  char*    R2    = ws + 5288192;              // T1 half2 (2265600) then T2 (906240)
  float2*  X21   = (float2*) (ws + 7553792);  // 453120 -> ends 8006912
  float2*  xfT   = (float2*) R1;
  float2*  X22   = (float2*) R1;
  __half2* T1    = (__half2*)R2;
  float2*  T2    = (float2*) R2;

  k1_prep<<<420, 256, 0, stream>>>(x1, w_conv, w_deconv, scwF1, scwF2, D0T, sgd, xfT);
  k_ana1<<<236, 256, 0, stream>>>(xfT, D0T, X21);
  k_core1<<<1800, 256, 0, stream>>>(X21, sgd, scwF1, T1);
  k_ana2<<<236, 256, 0, stream>>>(T1, D0T, X22);
  k_core2<<<1800, 256, 0, stream>>>(X22, sgd, scwF2, T2);
  k_synth2<<<120, 256, 0, stream>>>(T2, out);
}